// Round 11
// baseline (174.463 us; speedup 1.0000x reference)
//
#include <hip/hip_runtime.h>
#include <hip/hip_cooperative_groups.h>

namespace cg = cooperative_groups;

// ---------------------------------------------------------------------------
// GCN 2-layer forward. 7 launches:
//   k_zero:      cnt=0; WT = bf16(W1^T) [128][128]; WT2 = bf16(W2^T) pad [48][128]
//   k_histgemm1: block-split fusion -- blocks [0,nhb) histogram cnt[dst]++,
//                blocks [nhb,..) MFMA gemm1 H1b = bf16(x@W1) (independent work,
//                fills CUs idled by the latency-bound atomics)
//   k_scan:      cooperative (196 blocks): exscan(cnt) -> rowstart/cursor, dinv
//   k_scatter:   CSR (src,norm) int2 pairs grouped by dst
//   k_agg1:      AGGb = bf16(relu(b1 + H1b*dinv^2 + gather(H1b)))
//   k_gemm2:     H3b = bf16(AGGb@W2)  MFMA, LDS-free
//   k_agg2:      OUT = b2 + H3b*dinv^2 + gather(H3b)
// ---------------------------------------------------------------------------

typedef __attribute__((ext_vector_type(8))) short bf16x8;
typedef __attribute__((ext_vector_type(4))) float f32x4;

__device__ inline unsigned short f2bf(float x) {
    unsigned u = __float_as_uint(x);
    unsigned r = (u + 0x7FFFu + ((u >> 16) & 1u)) >> 16;   // round-nearest-even
    return (unsigned short)r;
}
__device__ inline float bflo(unsigned u) { return __uint_as_float(u << 16); }
__device__ inline float bfhi(unsigned u) { return __uint_as_float(u & 0xFFFF0000u); }

__device__ inline void fma8(float* acc, uint4 uv, float wt) {
    acc[0] = fmaf(bflo(uv.x), wt, acc[0]);
    acc[1] = fmaf(bfhi(uv.x), wt, acc[1]);
    acc[2] = fmaf(bflo(uv.y), wt, acc[2]);
    acc[3] = fmaf(bfhi(uv.y), wt, acc[3]);
    acc[4] = fmaf(bflo(uv.z), wt, acc[4]);
    acc[5] = fmaf(bfhi(uv.z), wt, acc[5]);
    acc[6] = fmaf(bflo(uv.w), wt, acc[6]);
    acc[7] = fmaf(bfhi(uv.w), wt, acc[7]);
}

// blocks [0,nb): zero cnt. [nb,nb+16): WT = W1^T. [nb+16,nb+24): WT2 = W2^T pad48.
__global__ __launch_bounds__(256) void k_zero(int* __restrict__ cnt,
                                              const float* __restrict__ W1,
                                              const float* __restrict__ W2,
                                              unsigned short* __restrict__ WT,
                                              unsigned short* __restrict__ WT2,
                                              int n, int nb) {
    int b = blockIdx.x;
    if (b < nb) {
        int i = b * 256 + threadIdx.x;
        if (i < n) cnt[i] = 0;
    } else if (b < nb + 16) {
        int idx = (b - nb) * 256 + threadIdx.x;        // 0..4095
        for (int i = idx; i < 128 * 128; i += 4096) {
            int k = i >> 7, c = i & 127;
            WT[c * 128 + k] = f2bf(W1[i]);
        }
    } else {
        int idx = (b - nb - 16) * 256 + threadIdx.x;   // 0..2047
        for (int i = idx; i < 48 * 128; i += 2048) {
            int c = i >> 7, k = i & 127;
            WT2[i] = (c < 40) ? f2bf(W2[k * 40 + c]) : (unsigned short)0;
        }
    }
}

// blocks [0,nhb): histogram. blocks [nhb,...): MFMA gemm1, 64 rows each.
__global__ __launch_bounds__(256) void k_histgemm1(
    const int* __restrict__ dst, int* __restrict__ cnt,
    const float* __restrict__ X, const unsigned short* __restrict__ WT,
    unsigned short* __restrict__ Hb, int n, int m, int nhb)
{
    if (blockIdx.x < nhb) {
        int i = blockIdx.x * 256 + threadIdx.x;
        if (i < m) atomicAdd(&cnt[dst[i]], 1);
        return;
    }

    const int gb = blockIdx.x - nhb;
    const int l  = threadIdx.x & 63;
    const int w  = threadIdx.x >> 6;
    const int rw = gb * 64 + w * 16;
    const int lr = l & 15;
    const int kq = l >> 4;

    int arow = rw + lr;
    if (arow > n - 1) arow = n - 1;              // clamp: garbage rows never written
    const float* xp = X + (size_t)arow * 128 + kq * 8;

    f32x4 acc[8];
#pragma unroll
    for (int j = 0; j < 8; ++j) acc[j] = (f32x4){0.f, 0.f, 0.f, 0.f};

#pragma unroll
    for (int kk = 0; kk < 4; ++kk) {
        float4 v0 = *(const float4*)(xp + kk * 32);
        float4 v1 = *(const float4*)(xp + kk * 32 + 4);
        bf16x8 a;
        a[0] = (short)f2bf(v0.x); a[1] = (short)f2bf(v0.y);
        a[2] = (short)f2bf(v0.z); a[3] = (short)f2bf(v0.w);
        a[4] = (short)f2bf(v1.x); a[5] = (short)f2bf(v1.y);
        a[6] = (short)f2bf(v1.z); a[7] = (short)f2bf(v1.w);
#pragma unroll
        for (int j = 0; j < 8; ++j) {
            const bf16x8 b = *(const bf16x8*)(WT + (size_t)(j * 16 + lr) * 128 + kk * 32 + kq * 8);
            acc[j] = __builtin_amdgcn_mfma_f32_16x16x32_bf16(a, b, acc[j], 0, 0, 0);
        }
    }

#pragma unroll
    for (int j = 0; j < 8; ++j) {
        int col = j * 16 + lr;
#pragma unroll
        for (int r4 = 0; r4 < 4; ++r4) {
            int rr = rw + kq * 4 + r4;
            if (rr < n) Hb[(size_t)rr * 128 + col] = f2bf(acc[j][r4]);
        }
    }
}

// cooperative scan: gridDim.x = nb = ceil(n/256) <= 256, one grid.sync
__global__ __launch_bounds__(256) void k_scan(
    const int* __restrict__ cnt, int* __restrict__ rowstart,
    int* __restrict__ cursor, float* __restrict__ dinv,
    int* __restrict__ bsum, int n, int m)
{
    cg::grid_group grid = cg::this_grid();
    __shared__ int s[256];
    const int t  = threadIdx.x;
    const int b  = blockIdx.x;
    const int i  = b * 256 + t;
    const int nb = gridDim.x;

    // P1: block-local scan + dinv
    int v = (i < n) ? cnt[i] : 0;
    if (i < n) dinv[i] = rsqrtf((float)v + 1.0f);
    s[t] = v;
    __syncthreads();
#pragma unroll
    for (int off = 1; off < 256; off <<= 1) {
        int x = s[t];
        if (t >= off) x += s[t - off];
        __syncthreads();
        s[t] = x;
        __syncthreads();
    }
    const int excl_local = s[t] - v;
    if (t == 255) bsum[b] = s[255];
    grid.sync();

    // P2: every block scans all block sums in LDS (redundant, cheap)
    s[t] = (t < nb) ? bsum[t] : 0;
    __syncthreads();
#pragma unroll
    for (int off = 1; off < 256; off <<= 1) {
        int x = s[t];
        if (t >= off) x += s[t - off];
        __syncthreads();
        s[t] = x;
        __syncthreads();
    }
    int excl_blocks = (b > 0) ? s[b - 1] : 0;
    if (i < n) {
        int val = excl_local + excl_blocks;
        rowstart[i] = val;
        cursor[i]   = val;
    }
    if (i == 0) rowstart[n] = m;
}

__global__ __launch_bounds__(256) void k_scatter(const int* __restrict__ src,
                                                 const int* __restrict__ dst,
                                                 const float* __restrict__ dinv,
                                                 int* __restrict__ cursor,
                                                 int2* __restrict__ epair, int m) {
    int e = blockIdx.x * 256 + threadIdx.x;
    if (e >= m) return;
    int s = src[e], d = dst[e];
    int pos = atomicAdd(&cursor[d], 1);
    epair[pos] = make_int2(s, __float_as_int(dinv[s] * dinv[d]));
}

// layer-1 aggregation: 16 lanes/row, 8 ch each, 4-way unrolled, ReLU, bf16 out
__global__ __launch_bounds__(256) void k_agg1(
    const int* __restrict__ rowstart, const int2* __restrict__ epair,
    const unsigned short* __restrict__ Hb, const float* __restrict__ B,
    const float* __restrict__ dinv, unsigned short* __restrict__ AGGb, int n)
{
    int t = threadIdx.x;
    int lane = t & 15;
    int r = blockIdx.x * 16 + (t >> 4);
    if (r >= n) return;
    float di = dinv[r], d2 = di * di;
    uint4 hu = *(const uint4*)&Hb[(size_t)r * 128 + lane * 8];
    float a0[8], a1[8] = {}, a2[8] = {}, a3[8] = {};
    {
        const float* bp = &B[lane * 8];
        float h[8] = {bflo(hu.x), bfhi(hu.x), bflo(hu.y), bfhi(hu.y),
                      bflo(hu.z), bfhi(hu.z), bflo(hu.w), bfhi(hu.w)};
#pragma unroll
        for (int c = 0; c < 8; ++c) a0[c] = fmaf(h[c], d2, bp[c]);
    }
    int j  = rowstart[r];
    int j1 = rowstart[r + 1];
    for (; j + 4 <= j1; j += 4) {
        int2 p0 = epair[j], p1 = epair[j + 1], p2 = epair[j + 2], p3 = epair[j + 3];
        uint4 u0 = *(const uint4*)&Hb[(size_t)p0.x * 128 + lane * 8];
        uint4 u1 = *(const uint4*)&Hb[(size_t)p1.x * 128 + lane * 8];
        uint4 u2 = *(const uint4*)&Hb[(size_t)p2.x * 128 + lane * 8];
        uint4 u3 = *(const uint4*)&Hb[(size_t)p3.x * 128 + lane * 8];
        fma8(a0, u0, __int_as_float(p0.y));
        fma8(a1, u1, __int_as_float(p1.y));
        fma8(a2, u2, __int_as_float(p2.y));
        fma8(a3, u3, __int_as_float(p3.y));
    }
    for (; j < j1; ++j) {
        int2 pe = epair[j];
        uint4 u = *(const uint4*)&Hb[(size_t)pe.x * 128 + lane * 8];
        fma8(a0, u, __int_as_float(pe.y));
    }
    unsigned o[4];
#pragma unroll
    for (int c = 0; c < 4; ++c) {
        float lo = fmaxf(a0[2*c]   + a1[2*c]   + a2[2*c]   + a3[2*c],   0.f);
        float hi = fmaxf(a0[2*c+1] + a1[2*c+1] + a2[2*c+1] + a3[2*c+1], 0.f);
        o[c] = (unsigned)f2bf(lo) | ((unsigned)f2bf(hi) << 16);
    }
    *(uint4*)&AGGb[(size_t)r * 128 + lane * 8] = make_uint4(o[0], o[1], o[2], o[3]);
}

// GEMM2 via MFMA bf16: AGGb[n,128] @ W2 -> H3b[n,40]. 64 rows/block, 4 waves.
__global__ __launch_bounds__(256) void k_gemm2(
    const unsigned short* __restrict__ AGGb, const unsigned short* __restrict__ WT2,
    unsigned short* __restrict__ H3b, int n)
{
    const int l  = threadIdx.x & 63;
    const int w  = threadIdx.x >> 6;
    const int rw = blockIdx.x * 64 + w * 16;
    const int lr = l & 15;
    const int kq = l >> 4;

    int arow = rw + lr;
    if (arow > n - 1) arow = n - 1;
    const unsigned short* ap = AGGb + (size_t)arow * 128 + kq * 8;

    f32x4 acc[3];
#pragma unroll
    for (int j = 0; j < 3; ++j) acc[j] = (f32x4){0.f, 0.f, 0.f, 0.f};

#pragma unroll
    for (int kk = 0; kk < 4; ++kk) {
        const bf16x8 a = *(const bf16x8*)(ap + kk * 32);
#pragma unroll
        for (int j = 0; j < 3; ++j) {
            const bf16x8 b = *(const bf16x8*)(WT2 + (size_t)(j * 16 + lr) * 128 + kk * 32 + kq * 8);
            acc[j] = __builtin_amdgcn_mfma_f32_16x16x32_bf16(a, b, acc[j], 0, 0, 0);
        }
    }

#pragma unroll
    for (int j = 0; j < 3; ++j) {
        int col = j * 16 + lr;
        if (col < 40) {
#pragma unroll
            for (int r4 = 0; r4 < 4; ++r4) {
                int rr = rw + kq * 4 + r4;
                if (rr < n) H3b[(size_t)rr * 40 + col] = f2bf(acc[j][r4]);
            }
        }
    }
}

// layer-2 aggregation: 5 lanes/row, 8 ch each (uint4 = 16B), 320-thread blocks
__global__ __launch_bounds__(320) void k_agg2(
    const int* __restrict__ rowstart, const int2* __restrict__ epair,
    const unsigned short* __restrict__ H3b, const float* __restrict__ B,
    const float* __restrict__ dinv, float* __restrict__ OUT, int n)
{
    int t = threadIdx.x;
    int r = blockIdx.x * 64 + t / 5;
    int q = t % 5;
    if (r >= n) return;
    float di = dinv[r], d2 = di * di;
    uint4 hu = *(const uint4*)&H3b[(size_t)r * 40 + q * 8];
    float a0[8], a1[8] = {}, a2[8] = {}, a3[8] = {};
    {
        const float* bp = &B[q * 8];
        float h[8] = {bflo(hu.x), bfhi(hu.x), bflo(hu.y), bfhi(hu.y),
                      bflo(hu.z), bfhi(hu.z), bflo(hu.w), bfhi(hu.w)};
#pragma unroll
        for (int c = 0; c < 8; ++c) a0[c] = fmaf(h[c], d2, bp[c]);
    }
    int j  = rowstart[r];
    int j1 = rowstart[r + 1];
    for (; j + 4 <= j1; j += 4) {
        int2 p0 = epair[j], p1 = epair[j + 1], p2 = epair[j + 2], p3 = epair[j + 3];
        uint4 u0 = *(const uint4*)&H3b[(size_t)p0.x * 40 + q * 8];
        uint4 u1 = *(const uint4*)&H3b[(size_t)p1.x * 40 + q * 8];
        uint4 u2 = *(const uint4*)&H3b[(size_t)p2.x * 40 + q * 8];
        uint4 u3 = *(const uint4*)&H3b[(size_t)p3.x * 40 + q * 8];
        fma8(a0, u0, __int_as_float(p0.y));
        fma8(a1, u1, __int_as_float(p1.y));
        fma8(a2, u2, __int_as_float(p2.y));
        fma8(a3, u3, __int_as_float(p3.y));
    }
    for (; j < j1; ++j) {
        int2 pe = epair[j];
        uint4 u = *(const uint4*)&H3b[(size_t)pe.x * 40 + q * 8];
        fma8(a0, u, __int_as_float(pe.y));
    }
    float o[8];
#pragma unroll
    for (int c = 0; c < 8; ++c) o[c] = a0[c] + a1[c] + a2[c] + a3[c];
    float* p = &OUT[(size_t)r * 40 + q * 8];
    *(float4*)(p)     = make_float4(o[0], o[1], o[2], o[3]);
    *(float4*)(p + 4) = make_float4(o[4], o[5], o[6], o[7]);
}

extern "C" void kernel_launch(void* const* d_in, const int* in_sizes, int n_in,
                              void* d_out, int out_size, void* d_ws, size_t ws_size,
                              hipStream_t stream) {
    const float* x  = (const float*)d_in[0];
    const int*   ei = (const int*)d_in[1];
    const float* W1 = (const float*)d_in[2];
    const float* b1 = (const float*)d_in[3];
    const float* W2 = (const float*)d_in[4];
    const float* b2 = (const float*)d_in[5];
    float* out = (float*)d_out;

    const int n = in_sizes[0] / 128;     // 50000
    const int m = in_sizes[1] / 2;       // 600000
    const int* src = ei;
    const int* dst = ei + m;
    const int nb  = (n + 255) / 256;     // 196
    const int nhb = (m + 255) / 256;     // 2344 hist blocks
    const int ngb = (n + 63) / 64;       // 782 gemm1 blocks

    char* p = (char*)d_ws;
    auto take = [&](size_t bytes) { char* q = p; p += (bytes + 255) & ~(size_t)255; return q; };
    int*   cnt      = (int*)take(sizeof(int) * n);
    int*   rowstart = (int*)take(sizeof(int) * (n + 1));
    int*   cursor   = (int*)take(sizeof(int) * n);
    int*   bsum     = (int*)take(sizeof(int) * 256);
    int2*  epair    = (int2*)take(sizeof(int2) * m);
    float* dinv     = (float*)take(sizeof(float) * n);
    unsigned short* WT  = (unsigned short*)take(sizeof(short) * 128 * 128);
    unsigned short* WT2 = (unsigned short*)take(sizeof(short) * 48 * 128);
    unsigned short* H1b = (unsigned short*)take(sizeof(short) * (size_t)n * 128);
    unsigned short* AGGb = (unsigned short*)take(sizeof(short) * (size_t)n * 128);
    unsigned short* H3b = H1b;           // alias: H1b dead after k_agg1

    k_zero     <<<nb + 24, 256, 0, stream>>>(cnt, W1, W2, WT, WT2, n, nb);
    k_histgemm1<<<nhb + ngb, 256, 0, stream>>>(dst, cnt, x, WT, H1b, n, m, nhb);

    {
        void* args[] = {(void*)&cnt, (void*)&rowstart, (void*)&cursor, (void*)&dinv,
                        (void*)&bsum, (void*)&n, (void*)&m};
        hipLaunchCooperativeKernel((void*)k_scan, dim3(nb), dim3(256), args, 0, stream);
    }

    k_scatter<<<nhb, 256, 0, stream>>>(src, dst, dinv, cursor, epair, m);
    k_agg1   <<<(n + 15) / 16, 256, 0, stream>>>(rowstart, epair, H1b, b1, dinv, AGGb, n);
    k_gemm2  <<<ngb, 256, 0, stream>>>(AGGb, WT2, H3b, n);
    k_agg2   <<<(n + 63) / 64, 320, 0, stream>>>(rowstart, epair, H3b, b2, dinv, out, n);
}

// Round 12
// 143.237 us; speedup vs baseline: 1.2180x; 1.2180x over previous
//
#include <hip/hip_runtime.h>

// ---------------------------------------------------------------------------
// GCN 2-layer forward. 8 launches (r10 base + agg1/gemm2 LDS fusion):
//   k_zero:       cnt=0; WT = bf16(W1^T) [128][128]; WT2 = bf16(W2^T) pad [48][128]
//   k_hist:       cnt[dst]++ (int atomics)
//   k_scan_local: block-local exscan + dinv
//   k_scan_add:   each block scans bsum in LDS, globalizes, inits cursor
//   k_scatter:    CSR (src,norm) int2 pairs grouped by dst
//   k_gemm1:      H1b = bf16(x@W1)   MFMA 16x16x32, LDS-free
//   k_agg1g2:     per 64-row block: AGG_lds = bf16(relu(b1 + H1b*dinv^2 +
//                 gather(H1b))) -> LDS tile -> MFMA @ WT2 -> H3b  (no AGG global)
//   k_agg2:       OUT = b2 + H3b*dinv^2 + gather(H3b)
// ---------------------------------------------------------------------------

typedef __attribute__((ext_vector_type(8))) short bf16x8;
typedef __attribute__((ext_vector_type(4))) float f32x4;

__device__ inline unsigned short f2bf(float x) {
    unsigned u = __float_as_uint(x);
    unsigned r = (u + 0x7FFFu + ((u >> 16) & 1u)) >> 16;   // round-nearest-even
    return (unsigned short)r;
}
__device__ inline float bflo(unsigned u) { return __uint_as_float(u << 16); }
__device__ inline float bfhi(unsigned u) { return __uint_as_float(u & 0xFFFF0000u); }

__device__ inline void fma8(float* acc, uint4 uv, float wt) {
    acc[0] = fmaf(bflo(uv.x), wt, acc[0]);
    acc[1] = fmaf(bfhi(uv.x), wt, acc[1]);
    acc[2] = fmaf(bflo(uv.y), wt, acc[2]);
    acc[3] = fmaf(bfhi(uv.y), wt, acc[3]);
    acc[4] = fmaf(bflo(uv.z), wt, acc[4]);
    acc[5] = fmaf(bfhi(uv.z), wt, acc[5]);
    acc[6] = fmaf(bflo(uv.w), wt, acc[6]);
    acc[7] = fmaf(bfhi(uv.w), wt, acc[7]);
}

// blocks [0,nb): zero cnt. [nb,nb+16): WT = W1^T. [nb+16,nb+24): WT2 = W2^T pad48.
__global__ __launch_bounds__(256) void k_zero(int* __restrict__ cnt,
                                              const float* __restrict__ W1,
                                              const float* __restrict__ W2,
                                              unsigned short* __restrict__ WT,
                                              unsigned short* __restrict__ WT2,
                                              int n, int nb) {
    int b = blockIdx.x;
    if (b < nb) {
        int i = b * 256 + threadIdx.x;
        if (i < n) cnt[i] = 0;
    } else if (b < nb + 16) {
        int idx = (b - nb) * 256 + threadIdx.x;        // 0..4095
        for (int i = idx; i < 128 * 128; i += 4096) {
            int k = i >> 7, c = i & 127;
            WT[c * 128 + k] = f2bf(W1[i]);
        }
    } else {
        int idx = (b - nb - 16) * 256 + threadIdx.x;   // 0..2047
        for (int i = idx; i < 48 * 128; i += 2048) {
            int c = i >> 7, k = i & 127;
            WT2[i] = (c < 40) ? f2bf(W2[k * 40 + c]) : (unsigned short)0;
        }
    }
}

__global__ __launch_bounds__(256) void k_hist(const int* __restrict__ dst,
                                              int* __restrict__ cnt, int m) {
    int i = blockIdx.x * 256 + threadIdx.x;
    if (i < m) atomicAdd(&cnt[dst[i]], 1);
}

__global__ __launch_bounds__(256) void k_scan_local(const int* __restrict__ cnt,
                                                    int* __restrict__ rowstart,
                                                    int* __restrict__ bsum,
                                                    float* __restrict__ dinv, int n) {
    __shared__ int s[256];
    int t = threadIdx.x;
    int i = blockIdx.x * 256 + t;
    int v = (i < n) ? cnt[i] : 0;
    if (i < n) dinv[i] = rsqrtf((float)v + 1.0f);
    s[t] = v;
    __syncthreads();
#pragma unroll
    for (int off = 1; off < 256; off <<= 1) {
        int x = s[t];
        if (t >= off) x += s[t - off];
        __syncthreads();
        s[t] = x;
        __syncthreads();
    }
    if (i < n) rowstart[i] = s[t] - v;        // block-local exclusive
    if (t == 255) bsum[blockIdx.x] = s[255];
}

// each block re-scans all block sums in LDS (nb <= 256), then globalizes
__global__ __launch_bounds__(256) void k_scan_add(int* __restrict__ rowstart,
                                                  const int* __restrict__ bsum,
                                                  int* __restrict__ cursor,
                                                  int n, int m, int nb) {
    __shared__ int s[256];
    int t = threadIdx.x;
    int b = blockIdx.x;
    s[t] = (t < nb) ? bsum[t] : 0;
    __syncthreads();
#pragma unroll
    for (int off = 1; off < 256; off <<= 1) {
        int x = s[t];
        if (t >= off) x += s[t - off];
        __syncthreads();
        s[t] = x;
        __syncthreads();
    }
    int excl = (b > 0) ? s[b - 1] : 0;        // sum of bsum[0..b)
    int i = b * 256 + t;
    if (i < n) {
        int v = rowstart[i] + excl;
        rowstart[i] = v;
        cursor[i]   = v;
    }
    if (i == 0) rowstart[n] = m;
}

__global__ __launch_bounds__(256) void k_scatter(const int* __restrict__ src,
                                                 const int* __restrict__ dst,
                                                 const float* __restrict__ dinv,
                                                 int* __restrict__ cursor,
                                                 int2* __restrict__ epair, int m) {
    int e = blockIdx.x * 256 + threadIdx.x;
    if (e >= m) return;
    int s = src[e], d = dst[e];
    int pos = atomicAdd(&cursor[d], 1);
    epair[pos] = make_int2(s, __float_as_int(dinv[s] * dinv[d]));
}

// GEMM1 via MFMA bf16: 64 rows/block, 4 waves, each wave 16 rows x 128 cols.
__global__ __launch_bounds__(256) void k_gemm1(
    const float* __restrict__ X, const unsigned short* __restrict__ WT,
    unsigned short* __restrict__ Hb, int n)
{
    const int l  = threadIdx.x & 63;
    const int w  = threadIdx.x >> 6;
    const int rw = blockIdx.x * 64 + w * 16;
    const int lr = l & 15;
    const int kq = l >> 4;

    int arow = rw + lr;
    if (arow > n - 1) arow = n - 1;              // clamp: garbage rows never written
    const float* xp = X + (size_t)arow * 128 + kq * 8;

    f32x4 acc[8];
#pragma unroll
    for (int j = 0; j < 8; ++j) acc[j] = (f32x4){0.f, 0.f, 0.f, 0.f};

#pragma unroll
    for (int kk = 0; kk < 4; ++kk) {
        float4 v0 = *(const float4*)(xp + kk * 32);
        float4 v1 = *(const float4*)(xp + kk * 32 + 4);
        bf16x8 a;
        a[0] = (short)f2bf(v0.x); a[1] = (short)f2bf(v0.y);
        a[2] = (short)f2bf(v0.z); a[3] = (short)f2bf(v0.w);
        a[4] = (short)f2bf(v1.x); a[5] = (short)f2bf(v1.y);
        a[6] = (short)f2bf(v1.z); a[7] = (short)f2bf(v1.w);
#pragma unroll
        for (int j = 0; j < 8; ++j) {
            const bf16x8 b = *(const bf16x8*)(WT + (size_t)(j * 16 + lr) * 128 + kk * 32 + kq * 8);
            acc[j] = __builtin_amdgcn_mfma_f32_16x16x32_bf16(a, b, acc[j], 0, 0, 0);
        }
    }

#pragma unroll
    for (int j = 0; j < 8; ++j) {
        int col = j * 16 + lr;
#pragma unroll
        for (int r4 = 0; r4 < 4; ++r4) {
            int rr = rw + kq * 4 + r4;
            if (rr < n) Hb[(size_t)rr * 128 + col] = f2bf(acc[j][r4]);
        }
    }
}

// Fused layer-1 aggregation + GEMM2. 64 rows per 256-thread block.
//   gather: 16 slots x 16 lanes, each slot does rows rr, rr+16, rr+32, rr+48;
//           bf16 result -> LDS tile[64][132] (pad 4 -> staggered banks)
//   matmul: 4 waves x 16 rows, MFMA 16x16x32, A from LDS, B from WT2 (L2)
__global__ __launch_bounds__(256) void k_agg1g2(
    const int* __restrict__ rowstart, const int2* __restrict__ epair,
    const unsigned short* __restrict__ Hb, const float* __restrict__ B1,
    const unsigned short* __restrict__ WT2, const float* __restrict__ dinv,
    unsigned short* __restrict__ H3b, int n)
{
    __shared__ unsigned short tile[64][132];    // bf16, +4 pad
    const int t  = threadIdx.x;
    const int r0 = blockIdx.x * 64;
    const int lane = t & 15;
    const int slot = t >> 4;

    for (int rr = slot; rr < 64; rr += 16) {
        int r = r0 + rr;
        if (r < n) {
            float di = dinv[r], d2 = di * di;
            uint4 hu = *(const uint4*)&Hb[(size_t)r * 128 + lane * 8];
            float a0[8], a1[8] = {}, a2[8] = {}, a3[8] = {};
            {
                const float* bp = &B1[lane * 8];
                float h[8] = {bflo(hu.x), bfhi(hu.x), bflo(hu.y), bfhi(hu.y),
                              bflo(hu.z), bfhi(hu.z), bflo(hu.w), bfhi(hu.w)};
#pragma unroll
                for (int c = 0; c < 8; ++c) a0[c] = fmaf(h[c], d2, bp[c]);
            }
            int j  = rowstart[r];
            int j1 = rowstart[r + 1];
            for (; j + 4 <= j1; j += 4) {
                int2 p0 = epair[j], p1 = epair[j + 1], p2 = epair[j + 2], p3 = epair[j + 3];
                uint4 u0 = *(const uint4*)&Hb[(size_t)p0.x * 128 + lane * 8];
                uint4 u1 = *(const uint4*)&Hb[(size_t)p1.x * 128 + lane * 8];
                uint4 u2 = *(const uint4*)&Hb[(size_t)p2.x * 128 + lane * 8];
                uint4 u3 = *(const uint4*)&Hb[(size_t)p3.x * 128 + lane * 8];
                fma8(a0, u0, __int_as_float(p0.y));
                fma8(a1, u1, __int_as_float(p1.y));
                fma8(a2, u2, __int_as_float(p2.y));
                fma8(a3, u3, __int_as_float(p3.y));
            }
            for (; j < j1; ++j) {
                int2 pe = epair[j];
                uint4 u = *(const uint4*)&Hb[(size_t)pe.x * 128 + lane * 8];
                fma8(a0, u, __int_as_float(pe.y));
            }
            unsigned o[4];
#pragma unroll
            for (int c = 0; c < 4; ++c) {
                float lo = fmaxf(a0[2*c]   + a1[2*c]   + a2[2*c]   + a3[2*c],   0.f);
                float hi = fmaxf(a0[2*c+1] + a1[2*c+1] + a2[2*c+1] + a3[2*c+1], 0.f);
                o[c] = (unsigned)f2bf(lo) | ((unsigned)f2bf(hi) << 16);
            }
            *(uint4*)&tile[rr][lane * 8] = make_uint4(o[0], o[1], o[2], o[3]);
        }
        // rows >= n: tile left uninitialized; MFMA output rows >= n never stored
    }
    __syncthreads();

    // MFMA phase: wave w handles rows rw..rw+15
    const int l  = t & 63;
    const int w  = t >> 6;
    const int rw = r0 + w * 16;
    const int lr = l & 15;
    const int kq = l >> 4;

    f32x4 acc[3];
#pragma unroll
    for (int j = 0; j < 3; ++j) acc[j] = (f32x4){0.f, 0.f, 0.f, 0.f};

#pragma unroll
    for (int kk = 0; kk < 4; ++kk) {
        const bf16x8 a = *(const bf16x8*)&tile[w * 16 + lr][kk * 32 + kq * 8];
#pragma unroll
        for (int j = 0; j < 3; ++j) {
            const bf16x8 b = *(const bf16x8*)(WT2 + (size_t)(j * 16 + lr) * 128 + kk * 32 + kq * 8);
            acc[j] = __builtin_amdgcn_mfma_f32_16x16x32_bf16(a, b, acc[j], 0, 0, 0);
        }
    }

#pragma unroll
    for (int j = 0; j < 3; ++j) {
        int col = j * 16 + lr;
        if (col < 40) {
#pragma unroll
            for (int r4 = 0; r4 < 4; ++r4) {
                int rr = rw + kq * 4 + r4;
                if (rr < n) H3b[(size_t)rr * 40 + col] = f2bf(acc[j][r4]);
            }
        }
    }
}

// layer-2 aggregation: 5 lanes/row, 8 ch each (uint4 = 16B), 320-thread blocks
__global__ __launch_bounds__(320) void k_agg2(
    const int* __restrict__ rowstart, const int2* __restrict__ epair,
    const unsigned short* __restrict__ H3b, const float* __restrict__ B,
    const float* __restrict__ dinv, float* __restrict__ OUT, int n)
{
    int t = threadIdx.x;
    int r = blockIdx.x * 64 + t / 5;
    int q = t % 5;
    if (r >= n) return;
    float di = dinv[r], d2 = di * di;
    uint4 hu = *(const uint4*)&H3b[(size_t)r * 40 + q * 8];
    float a0[8], a1[8] = {}, a2[8] = {}, a3[8] = {};
    {
        const float* bp = &B[q * 8];
        float h[8] = {bflo(hu.x), bfhi(hu.x), bflo(hu.y), bfhi(hu.y),
                      bflo(hu.z), bfhi(hu.z), bflo(hu.w), bfhi(hu.w)};
#pragma unroll
        for (int c = 0; c < 8; ++c) a0[c] = fmaf(h[c], d2, bp[c]);
    }
    int j  = rowstart[r];
    int j1 = rowstart[r + 1];
    for (; j + 4 <= j1; j += 4) {
        int2 p0 = epair[j], p1 = epair[j + 1], p2 = epair[j + 2], p3 = epair[j + 3];
        uint4 u0 = *(const uint4*)&H3b[(size_t)p0.x * 40 + q * 8];
        uint4 u1 = *(const uint4*)&H3b[(size_t)p1.x * 40 + q * 8];
        uint4 u2 = *(const uint4*)&H3b[(size_t)p2.x * 40 + q * 8];
        uint4 u3 = *(const uint4*)&H3b[(size_t)p3.x * 40 + q * 8];
        fma8(a0, u0, __int_as_float(p0.y));
        fma8(a1, u1, __int_as_float(p1.y));
        fma8(a2, u2, __int_as_float(p2.y));
        fma8(a3, u3, __int_as_float(p3.y));
    }
    for (; j < j1; ++j) {
        int2 pe = epair[j];
        uint4 u = *(const uint4*)&H3b[(size_t)pe.x * 40 + q * 8];
        fma8(a0, u, __int_as_float(pe.y));
    }
    float o[8];
#pragma unroll
    for (int c = 0; c < 8; ++c) o[c] = a0[c] + a1[c] + a2[c] + a3[c];
    float* p = &OUT[(size_t)r * 40 + q * 8];
    *(float4*)(p)     = make_float4(o[0], o[1], o[2], o[3]);
    *(float4*)(p + 4) = make_float4(o[4], o[5], o[6], o[7]);
}

extern "C" void kernel_launch(void* const* d_in, const int* in_sizes, int n_in,
                              void* d_out, int out_size, void* d_ws, size_t ws_size,
                              hipStream_t stream) {
    const float* x  = (const float*)d_in[0];
    const int*   ei = (const int*)d_in[1];
    const float* W1 = (const float*)d_in[2];
    const float* b1 = (const float*)d_in[3];
    const float* W2 = (const float*)d_in[4];
    const float* b2 = (const float*)d_in[5];
    float* out = (float*)d_out;

    const int n = in_sizes[0] / 128;     // 50000
    const int m = in_sizes[1] / 2;       // 600000
    const int* src = ei;
    const int* dst = ei + m;
    const int nb = (n + 255) / 256;      // 196

    char* p = (char*)d_ws;
    auto take = [&](size_t bytes) { char* q = p; p += (bytes + 255) & ~(size_t)255; return q; };
    int*   cnt      = (int*)take(sizeof(int) * n);
    int*   rowstart = (int*)take(sizeof(int) * (n + 1));
    int*   cursor   = (int*)take(sizeof(int) * n);
    int*   bsum     = (int*)take(sizeof(int) * 256);
    int2*  epair    = (int2*)take(sizeof(int2) * m);
    float* dinv     = (float*)take(sizeof(float) * n);
    unsigned short* WT  = (unsigned short*)take(sizeof(short) * 128 * 128);
    unsigned short* WT2 = (unsigned short*)take(sizeof(short) * 48 * 128);
    unsigned short* H1b = (unsigned short*)take(sizeof(short) * (size_t)n * 128);
    unsigned short* H3b = (unsigned short*)take(sizeof(short) * (size_t)n * 40);

    k_zero      <<<nb + 24, 256, 0, stream>>>(cnt, W1, W2, WT, WT2, n, nb);
    k_hist      <<<(m + 255) / 256, 256, 0, stream>>>(dst, cnt, m);
    k_scan_local<<<nb, 256, 0, stream>>>(cnt, rowstart, bsum, dinv, n);
    k_scan_add  <<<nb, 256, 0, stream>>>(rowstart, bsum, cursor, n, m, nb);
    k_scatter   <<<(m + 255) / 256, 256, 0, stream>>>(src, dst, dinv, cursor, epair, m);

    k_gemm1 <<<(n + 63) / 64, 256, 0, stream>>>(x, WT, H1b, n);
    k_agg1g2<<<(n + 63) / 64, 256, 0, stream>>>(rowstart, epair, H1b, b1, WT2, dinv, H3b, n);
    k_agg2  <<<(n + 63) / 64, 320, 0, stream>>>(rowstart, epair, H3b, b2, dinv, out, n);
}